// Round 4
// baseline (88.716 us; speedup 1.0000x reference)
//
#include <hip/hip_runtime.h>

// Problem constants (fixed shapes from setup_inputs)
constexpr int NB = 8;     // batch
constexpr int ND = 1024;  // d = 32*32 cells
constexpr int NS = 500;   // noise samples n
constexpr int NK = 16;    // k
constexpr int NC = 3;     // channels
constexpr int NH = 1024;  // H
constexpr int NW = 1024;  // W
constexpr int NP = 64;    // patch size
constexpr int PTOP = 16;  // (p - sh)/2
constexpr int PLEFT = 16; // (p - sw)/2
constexpr float SIGMA = 0.05f;

// ---------------- Phase 1: normalize (blocks 0-7) + zero counts (all 64) ----------------
__global__ void normalize_kernel(const float* __restrict__ scores,
                                 float* __restrict__ s_norm,
                                 int* __restrict__ counts) {
    int blk = blockIdx.x;   // 64 blocks
    int t = threadIdx.x;

    // zero the counts buffer: 8*16*1024 ints = 32768 int4; 512 int4 per block
    int4 z4 = make_int4(0, 0, 0, 0);
    ((int4*)counts)[blk * 512 + t] = z4;
    ((int4*)counts)[blk * 512 + 256 + t] = z4;

    if (blk >= NB) return;
    int b = blk;
    float v[4];
#pragma unroll
    for (int q = 0; q < 4; q++) v[q] = scores[b * ND + t + 256 * q];
    float mn = fminf(fminf(v[0], v[1]), fminf(v[2], v[3]));
    float mx = fmaxf(fmaxf(v[0], v[1]), fmaxf(v[2], v[3]));
#pragma unroll
    for (int off = 1; off < 64; off <<= 1) {
        mn = fminf(mn, __shfl_xor(mn, off));
        mx = fmaxf(mx, __shfl_xor(mx, off));
    }
    __shared__ float smn[4], smx[4];
    int wave = t >> 6, lane = t & 63;
    if (lane == 0) { smn[wave] = mn; smx[wave] = mx; }
    __syncthreads();
    mn = fminf(fminf(smn[0], smn[1]), fminf(smn[2], smn[3]));
    mx = fmaxf(fmaxf(smx[0], smx[1]), fmaxf(smx[2], smx[3]));
    float den = mx - mn + 1e-5f;
#pragma unroll
    for (int q = 0; q < 4; q++)
        s_norm[b * ND + t + 256 * q] = (v[q] - mn) / den;
}

// ---------------- Phase 2: wave-per-sample top-16 -> integer histogram ----------------
__global__ void topk_kernel(const float* __restrict__ s_norm,
                            const float* __restrict__ noise,
                            int* __restrict__ counts) {
    int t = threadIdx.x;
    int wave = t >> 6, lane = t & 63;
    int sid = blockIdx.x * 4 + wave;          // 0 .. NB*NS-1 (grid is exact)
    int b = sid / NS;

    const float* sp = s_norm + b * ND;
    const float* npp = noise + (size_t)sid * ND;

    float v[16];
#pragma unroll
    for (int q = 0; q < 16; q++) {
        int j = q * 64 + lane;
        v[q] = sp[j] + npp[j] * SIGMA;
    }

    int myj = 0x7fffffff;
    for (int it = 0; it < NK; it++) {
        float bv = v[0];
        int bq = 0;
#pragma unroll
        for (int q = 1; q < 16; q++)
            if (v[q] > bv) { bv = v[q]; bq = q; }
        int bj = bq * 64 + lane;
#pragma unroll
        for (int off = 1; off < 64; off <<= 1) {
            float ov = __shfl_xor(bv, off);
            int oj = __shfl_xor(bj, off);
            if (ov > bv || (ov == bv && oj < bj)) { bv = ov; bj = oj; }
        }
        if (lane == it) myj = bj;
        int wq = bj >> 6, wl = bj & 63;
#pragma unroll
        for (int q = 0; q < 16; q++)
            v[q] = (q == wq && lane == wl) ? -1e30f : v[q];
    }

    int rank = 0;
#pragma unroll
    for (int u = 0; u < NK; u++) {
        int other = __shfl(myj, u);
        rank += (other < myj) ? 1 : 0;
    }
    if (lane < NK)
        atomicAdd(&counts[(b * NK + rank) * ND + myj], 1);
}

// ---------------- Phase 2.5: per-batch union of nonzero cells ----------------
// Block per b. Thread t owns cells [4t,4t+4). Entry = cell with ANY nonzero
// count across the 16 ranks. Deterministic block prefix-scan -> ascending cell
// order. Per entry: cell id + 16 float weights (count/500).
__global__ void union_kernel(const int* __restrict__ counts,
                             int* __restrict__ ucell,
                             float* __restrict__ uw,
                             int* __restrict__ nunion) {
    int b = blockIdx.x;
    int t = threadIdx.x;
    int lane = t & 63, wave = t >> 6;
    const int* cp = counts + b * NK * ND;

    unsigned nz = 0;
    for (int kk = 0; kk < NK; kk++) {
        int4 c4 = *(const int4*)(cp + kk * ND + t * 4);
        if (c4.x) nz |= 1;
        if (c4.y) nz |= 2;
        if (c4.z) nz |= 4;
        if (c4.w) nz |= 8;
    }
    int cnt = __popc(nz);
    int incl = cnt;
#pragma unroll
    for (int off = 1; off < 64; off <<= 1) {
        int o = __shfl_up(incl, off);
        if (lane >= off) incl += o;
    }
    int excl = incl - cnt;
    __shared__ int wtot[4];
    if (lane == 63) wtot[wave] = incl;
    __syncthreads();
    int base = 0;
    for (int w = 0; w < wave; w++) base += wtot[w];
    int pos = base + excl;

    const float invn = 1.0f / (float)NS;
    int* up = ucell + b * ND;
    float* wp = uw + (size_t)b * ND * NK;
#pragma unroll
    for (int q = 0; q < 4; q++) {
        if (nz & (1u << q)) {
            int cell = t * 4 + q;
            up[pos] = cell;
            for (int kk = 0; kk < NK; kk++)
                wp[(size_t)pos * NK + kk] = (float)cp[kk * ND + cell] * invn;
            pos++;
        }
    }
    if (t == 0) nunion[b] = wtot[0] + wtot[1] + wtot[2] + wtot[3];
}

// ---------------- Phase 3: union gather ----------------
// Block per (b, c, kh, gg): 8*3*2*16 = 768 blocks. Threads: x = t&63,
// yq = t>>6 -> row y = gg*4+yq. Each thread: 1 load per union entry feeds
// 8 FMAs (kk = kh*8 .. +8). Weights staged per-chunk in LDS (broadcast reads).
constexpr int CH = 256;  // chunk of union entries staged in LDS
__global__ void gather_kernel(const int* __restrict__ ucell,
                              const float* __restrict__ uw,
                              const int* __restrict__ nunion,
                              const float* __restrict__ x_high,
                              float* __restrict__ out) {
    int blk = blockIdx.x;            // ((b*3 + c)*2 + kh)*16 + gg
    int gg = blk & 15;
    int kh = (blk >> 4) & 1;
    int c = (blk >> 5) % NC;
    int b = blk / (NC * 2 * 16);
    int t = threadIdx.x;
    int x = t & 63;
    int yq = t >> 6;
    int y = gg * 4 + yq;

    int U = nunion[b];
    __shared__ int lc[CH];
    __shared__ float lw[CH][8];

    const float* xp = x_high + (size_t)(b * NC + c) * NH * NW;
    int xm = x - PLEFT;
    int ym = y - PTOP;

    float acc[8];
#pragma unroll
    for (int q = 0; q < 8; q++) acc[q] = 0.f;

    for (int base = 0; base < U; base += CH) {
        int m = min(CH, U - base);
        __syncthreads();
        if (t < m) {
            lc[t] = ucell[b * ND + base + t];
            const float4* wsrc =
                (const float4*)(uw + ((size_t)b * ND + base + t) * NK + kh * 8);
            *(float4*)&lw[t][0] = wsrc[0];
            *(float4*)&lw[t][4] = wsrc[1];
        }
        __syncthreads();
#pragma unroll 4
        for (int e = 0; e < m; e++) {
            int cell = lc[e];
            int col = ((cell & 31) << 5) + xm;
            int row = ((cell >> 5) << 5) + ym;
            bool ok = ((unsigned)col < (unsigned)NW) & ((unsigned)row < (unsigned)NH);
            int rc = min(max(row, 0), NH - 1);
            int cc = min(max(col, 0), NW - 1);
            float v = xp[(rc << 10) + cc];
            v = ok ? v : 0.f;
            float4 wa = *(const float4*)&lw[e][0];
            float4 wb = *(const float4*)&lw[e][4];
            acc[0] += wa.x * v; acc[1] += wa.y * v;
            acc[2] += wa.z * v; acc[3] += wa.w * v;
            acc[4] += wb.x * v; acc[5] += wb.y * v;
            acc[6] += wb.z * v; acc[7] += wb.w * v;
        }
    }

#pragma unroll
    for (int q = 0; q < 8; q++) {
        int o = ((b * NK + kh * 8 + q) * NC + c) * (NP * NP) + y * NP + x;
        out[o] = acc[q];
    }
}

extern "C" void kernel_launch(void* const* d_in, const int* in_sizes, int n_in,
                              void* d_out, int out_size, void* d_ws, size_t ws_size,
                              hipStream_t stream) {
    const float* scores = (const float*)d_in[0];
    const float* x_high = (const float*)d_in[1];
    const float* noise  = (const float*)d_in[2];

    char* ws = (char*)d_ws;
    float* s_norm = (float*)ws;                            // 32 KB
    int* counts   = (int*)(ws + 32 * 1024);                // 512 KB (int4-aligned)
    int* ucell    = (int*)(ws + 544 * 1024);               // 32 KB
    float* uw     = (float*)(ws + 576 * 1024);             // 512 KB
    int* nunion   = (int*)(ws + 1088 * 1024);              // 32 B

    normalize_kernel<<<64, 256, 0, stream>>>(scores, s_norm, counts);
    topk_kernel<<<NB * NS / 4, 256, 0, stream>>>(s_norm, noise, counts);
    union_kernel<<<NB, 256, 0, stream>>>(counts, ucell, uw, nunion);
    gather_kernel<<<NB * NC * 2 * 16, 256, 0, stream>>>(ucell, uw, nunion, x_high,
                                                        (float*)d_out);
}

// Round 5
// 62.403 us; speedup vs baseline: 1.4217x; 1.4217x over previous
//
#include <hip/hip_runtime.h>

// Problem constants (fixed shapes from setup_inputs)
constexpr int NB = 8;     // batch
constexpr int ND = 1024;  // d = 32*32 cells
constexpr int NS = 500;   // noise samples n
constexpr int NK = 16;    // k
constexpr int NC = 3;     // channels
constexpr int NH = 1024;  // H
constexpr int NW = 1024;  // W
constexpr int NP = 64;    // patch size
constexpr int PTOP = 16;  // (p - sh)/2
constexpr int PLEFT = 16; // (p - sw)/2
constexpr float SIGMA = 0.05f;
constexpr int OUT_ELEMS = NB * NK * NC * NP * NP;  // 1,572,864 floats

// ---- Phase 1: normalize (blocks 0-7) + zero counts + zero out (all 64) ----
__global__ void normalize_kernel(const float* __restrict__ scores,
                                 float* __restrict__ s_norm,
                                 int* __restrict__ counts,
                                 float* __restrict__ out) {
    int blk = blockIdx.x;   // 64 blocks
    int t = threadIdx.x;

    // zero counts: 8*16*1024 ints = 32768 int4; 512 int4 per block
    int4 z4 = make_int4(0, 0, 0, 0);
    ((int4*)counts)[blk * 512 + t] = z4;
    ((int4*)counts)[blk * 512 + 256 + t] = z4;
    // zero out: 393216 float4 / (64*256 threads) = 24 float4 per thread
    float4 f4 = make_float4(0.f, 0.f, 0.f, 0.f);
#pragma unroll
    for (int q = 0; q < 24; q++)
        ((float4*)out)[(size_t)(blk * 256 + t) + (size_t)q * 16384] = f4;

    if (blk >= NB) return;
    int b = blk;
    float v[4];
#pragma unroll
    for (int q = 0; q < 4; q++) v[q] = scores[b * ND + t + 256 * q];
    float mn = fminf(fminf(v[0], v[1]), fminf(v[2], v[3]));
    float mx = fmaxf(fmaxf(v[0], v[1]), fmaxf(v[2], v[3]));
#pragma unroll
    for (int off = 1; off < 64; off <<= 1) {
        mn = fminf(mn, __shfl_xor(mn, off));
        mx = fmaxf(mx, __shfl_xor(mx, off));
    }
    __shared__ float smn[4], smx[4];
    int wave = t >> 6, lane = t & 63;
    if (lane == 0) { smn[wave] = mn; smx[wave] = mx; }
    __syncthreads();
    mn = fminf(fminf(smn[0], smn[1]), fminf(smn[2], smn[3]));
    mx = fmaxf(fmaxf(smx[0], smx[1]), fmaxf(smx[2], smx[3]));
    float den = mx - mn + 1e-5f;
#pragma unroll
    for (int q = 0; q < 4; q++)
        s_norm[b * ND + t + 256 * q] = (v[q] - mn) / den;
}

// ---------------- Phase 2: wave-per-sample top-16 -> integer histogram ----------------
__global__ void topk_kernel(const float* __restrict__ s_norm,
                            const float* __restrict__ noise,
                            int* __restrict__ counts) {
    int t = threadIdx.x;
    int wave = t >> 6, lane = t & 63;
    int sid = blockIdx.x * 4 + wave;          // 0 .. NB*NS-1 (grid is exact)
    int b = sid / NS;

    const float* sp = s_norm + b * ND;
    const float* npp = noise + (size_t)sid * ND;

    float v[16];
#pragma unroll
    for (int q = 0; q < 16; q++) {
        int j = q * 64 + lane;
        v[q] = sp[j] + npp[j] * SIGMA;
    }

    int myj = 0x7fffffff;
    for (int it = 0; it < NK; it++) {
        float bv = v[0];
        int bq = 0;
#pragma unroll
        for (int q = 1; q < 16; q++)
            if (v[q] > bv) { bv = v[q]; bq = q; }
        int bj = bq * 64 + lane;
#pragma unroll
        for (int off = 1; off < 64; off <<= 1) {
            float ov = __shfl_xor(bv, off);
            int oj = __shfl_xor(bj, off);
            if (ov > bv || (ov == bv && oj < bj)) { bv = ov; bj = oj; }
        }
        if (lane == it) myj = bj;
        int wq = bj >> 6, wl = bj & 63;
#pragma unroll
        for (int q = 0; q < 16; q++)
            v[q] = (q == wq && lane == wl) ? -1e30f : v[q];
    }

    int rank = 0;
#pragma unroll
    for (int u = 0; u < NK; u++) {
        int other = __shfl(myj, u);
        rank += (other < myj) ? 1 : 0;
    }
    if (lane < NK)
        atomicAdd(&counts[(b * NK + rank) * ND + myj], 1);
}

// ---------------- Phase 2.5: per-batch union of nonzero cells ----------------
// Block per b. Entry = packed (i<<15)|(j<<5)|edge_flags (base byte-address of
// the cell's patch origin in the image, low 4 bits = {i==0,i==31,j==0,j==31}).
// Plus 16 f32 weights (count/500) per entry. Ascending cell order (prefix scan).
__global__ void union_kernel(const int* __restrict__ counts,
                             int* __restrict__ ucell,
                             float* __restrict__ uw,
                             int* __restrict__ nunion) {
    int b = blockIdx.x;
    int t = threadIdx.x;
    int lane = t & 63, wave = t >> 6;
    const int* cp = counts + b * NK * ND;

    unsigned nz = 0;
    for (int kk = 0; kk < NK; kk++) {
        int4 c4 = *(const int4*)(cp + kk * ND + t * 4);
        if (c4.x) nz |= 1;
        if (c4.y) nz |= 2;
        if (c4.z) nz |= 4;
        if (c4.w) nz |= 8;
    }
    int cnt = __popc(nz);
    int incl = cnt;
#pragma unroll
    for (int off = 1; off < 64; off <<= 1) {
        int o = __shfl_up(incl, off);
        if (lane >= off) incl += o;
    }
    int excl = incl - cnt;
    __shared__ int wtot[4];
    if (lane == 63) wtot[wave] = incl;
    __syncthreads();
    int base = 0;
    for (int w = 0; w < wave; w++) base += wtot[w];
    int pos = base + excl;

    const float invn = 1.0f / (float)NS;
    int* up = ucell + b * ND;
    float* wp = uw + (size_t)b * ND * NK;
#pragma unroll
    for (int q = 0; q < 4; q++) {
        if (nz & (1u << q)) {
            int cell = t * 4 + q;
            int i = cell >> 5, j = cell & 31;
            int ent = (i << 15) | (j << 5) |
                      ((i == 0) ? 1 : 0) | ((i == 31) ? 2 : 0) |
                      ((j == 0) ? 4 : 0) | ((j == 31) ? 8 : 0);
            up[pos] = ent;
            for (int kk = 0; kk < NK; kk++)
                wp[(size_t)pos * NK + kk] = (float)cp[kk * ND + cell] * invn;
            pos++;
        }
    }
    if (t == 0) nunion[b] = wtot[0] + wtot[1] + wtot[2] + wtot[3];
}

// ---------------- Phase 3: union gather, all 16 kk per thread ----------------
// Grid: blk = i32*24 + bc, bc = b*3+c (so all 32 blocks of one (b,c) image hit
// the same XCD: 24 % 8 == 0), i32 = gg(16) + 16*chunk(2). Thread: x = t&63,
// y = gg*4 + (t>>6). Per union entry: 1 coalesced load feeds 16 FMAs; entry
// word and weights are wave-uniform -> scalar loads (SMEM pipe, no LDS).
// Each block handles half the entry list; results combined via atomicAdd into
// zeroed out (exactly 2 addends per element -> bitwise deterministic).
__global__ void gather_kernel(const int* __restrict__ ucell,
                              const float* __restrict__ uw,
                              const int* __restrict__ nunion,
                              const float* __restrict__ x_high,
                              float* __restrict__ out) {
    int blk = blockIdx.x;
    int bc = blk % 24;
    int i32 = blk / 24;          // 0..31
    int gg = i32 & 15;
    int chunk = i32 >> 4;
    int b = bc / 3, c = bc % 3;
    int t = threadIdx.x;
    int x = t & 63;
    int y = gg * 4 + (t >> 6);

    int U = nunion[b];
    int half = U >> 1;
    int e0 = chunk ? half : 0;
    int e1 = chunk ? U : half;

    const float* xp = x_high + (size_t)bc * (NH * NW);
    int ym = y - PTOP;           // [-16, 48)
    int xm = x - PLEFT;          // [-16, 48)
    int off = ym * NW + xm;
    int mask = ((ym < 0) ? 1 : 0) | ((ym >= 32) ? 2 : 0) |
               ((xm < 0) ? 4 : 0) | ((xm >= 32) ? 8 : 0);

    const int* up = ucell + b * ND;
    const float* wp = uw + (size_t)b * ND * NK;

    float acc[16];
#pragma unroll
    for (int q = 0; q < 16; q++) acc[q] = 0.f;

#pragma unroll 2
    for (int e = e0; e < e1; e++) {
        int ent = up[e];                       // uniform -> s_load
        bool ok = (ent & mask) == 0;
        int idx = (ent & ~15) + off;
        idx = ok ? idx : 0;
        float v = xp[idx];
        v = ok ? v : 0.f;
#pragma unroll
        for (int q = 0; q < 16; q++)
            acc[q] += wp[(size_t)e * NK + q] * v;  // uniform weights -> s_load
    }

#pragma unroll
    for (int q = 0; q < 16; q++) {
        int o = ((b * NK + q) * NC + c) * (NP * NP) + y * NP + x;
        atomicAdd(&out[o], acc[q]);
    }
}

extern "C" void kernel_launch(void* const* d_in, const int* in_sizes, int n_in,
                              void* d_out, int out_size, void* d_ws, size_t ws_size,
                              hipStream_t stream) {
    const float* scores = (const float*)d_in[0];
    const float* x_high = (const float*)d_in[1];
    const float* noise  = (const float*)d_in[2];

    char* ws = (char*)d_ws;
    float* s_norm = (float*)ws;                            // 32 KB
    int* counts   = (int*)(ws + 32 * 1024);                // 512 KB (int4-aligned)
    int* ucell    = (int*)(ws + 544 * 1024);               // 32 KB
    float* uw     = (float*)(ws + 576 * 1024);             // 512 KB
    int* nunion   = (int*)(ws + 1088 * 1024);              // 32 B

    normalize_kernel<<<64, 256, 0, stream>>>(scores, s_norm, counts, (float*)d_out);
    topk_kernel<<<NB * NS / 4, 256, 0, stream>>>(s_norm, noise, counts);
    union_kernel<<<NB, 256, 0, stream>>>(counts, ucell, uw, nunion);
    gather_kernel<<<24 * 32, 256, 0, stream>>>(ucell, uw, nunion, x_high,
                                               (float*)d_out);
}

// Round 6
// 57.569 us; speedup vs baseline: 1.5410x; 1.0840x over previous
//
#include <hip/hip_runtime.h>

// Problem constants (fixed shapes from setup_inputs)
constexpr int NB = 8;     // batch
constexpr int ND = 1024;  // d = 32*32 cells
constexpr int NS = 500;   // noise samples n
constexpr int NK = 16;    // k
constexpr int NC = 3;     // channels
constexpr int NH = 1024;  // H
constexpr int NW = 1024;  // W
constexpr int NP = 64;    // patch size
constexpr int PTOP = 16;  // (p - sh)/2
constexpr int PLEFT = 16; // (p - sw)/2
constexpr float SIGMA = 0.05f;

// ---- Phase 1: normalize (blocks 0-7) + zero counts (all 64 blocks) ----
__global__ void normalize_kernel(const float* __restrict__ scores,
                                 float* __restrict__ s_norm,
                                 int* __restrict__ counts) {
    int blk = blockIdx.x;   // 64 blocks
    int t = threadIdx.x;

    // zero counts: 8*16*1024 ints = 32768 int4; 512 int4 per block
    int4 z4 = make_int4(0, 0, 0, 0);
    ((int4*)counts)[blk * 512 + t] = z4;
    ((int4*)counts)[blk * 512 + 256 + t] = z4;

    if (blk >= NB) return;
    int b = blk;
    float v[4];
#pragma unroll
    for (int q = 0; q < 4; q++) v[q] = scores[b * ND + t + 256 * q];
    float mn = fminf(fminf(v[0], v[1]), fminf(v[2], v[3]));
    float mx = fmaxf(fmaxf(v[0], v[1]), fmaxf(v[2], v[3]));
#pragma unroll
    for (int off = 1; off < 64; off <<= 1) {
        mn = fminf(mn, __shfl_xor(mn, off));
        mx = fmaxf(mx, __shfl_xor(mx, off));
    }
    __shared__ float smn[4], smx[4];
    int wave = t >> 6, lane = t & 63;
    if (lane == 0) { smn[wave] = mn; smx[wave] = mx; }
    __syncthreads();
    mn = fminf(fminf(smn[0], smn[1]), fminf(smn[2], smn[3]));
    mx = fmaxf(fmaxf(smx[0], smx[1]), fmaxf(smx[2], smx[3]));
    float den = mx - mn + 1e-5f;
#pragma unroll
    for (int q = 0; q < 4; q++)
        s_norm[b * ND + t + 256 * q] = (v[q] - mn) / den;
}

// ---------------- Phase 2: wave-per-sample top-16 -> integer histogram ----------------
__global__ void topk_kernel(const float* __restrict__ s_norm,
                            const float* __restrict__ noise,
                            int* __restrict__ counts) {
    int t = threadIdx.x;
    int wave = t >> 6, lane = t & 63;
    int sid = blockIdx.x * 4 + wave;          // 0 .. NB*NS-1 (grid is exact)
    int b = sid / NS;

    const float* sp = s_norm + b * ND;
    const float* npp = noise + (size_t)sid * ND;

    float v[16];
#pragma unroll
    for (int q = 0; q < 16; q++) {
        int j = q * 64 + lane;
        v[q] = sp[j] + npp[j] * SIGMA;
    }

    int myj = 0x7fffffff;
    for (int it = 0; it < NK; it++) {
        float bv = v[0];
        int bq = 0;
#pragma unroll
        for (int q = 1; q < 16; q++)
            if (v[q] > bv) { bv = v[q]; bq = q; }
        int bj = bq * 64 + lane;
#pragma unroll
        for (int off = 1; off < 64; off <<= 1) {
            float ov = __shfl_xor(bv, off);
            int oj = __shfl_xor(bj, off);
            if (ov > bv || (ov == bv && oj < bj)) { bv = ov; bj = oj; }
        }
        if (lane == it) myj = bj;
        int wq = bj >> 6, wl = bj & 63;
#pragma unroll
        for (int q = 0; q < 16; q++)
            v[q] = (q == wq && lane == wl) ? -1e30f : v[q];
    }

    int rank = 0;
#pragma unroll
    for (int u = 0; u < NK; u++) {
        int other = __shfl(myj, u);
        rank += (other < myj) ? 1 : 0;
    }
    if (lane < NK)
        atomicAdd(&counts[(b * NK + rank) * ND + myj], 1);
}

// ---------------- Phase 2.5: per-batch union of nonzero cells ----------------
// Block per b. Entry = packed (i<<15)|(j<<5)|edge_flags (base address offset of
// the cell's origin in the image; low 4 bits = {i==0,i==31,j==0,j==31}).
// Plus 16 f32 weights (count/500) per entry, laid out [entry][16].
__global__ void union_kernel(const int* __restrict__ counts,
                             int* __restrict__ ucell,
                             float* __restrict__ uw,
                             int* __restrict__ nunion) {
    int b = blockIdx.x;
    int t = threadIdx.x;
    int lane = t & 63, wave = t >> 6;
    const int* cp = counts + b * NK * ND;

    unsigned nz = 0;
    for (int kk = 0; kk < NK; kk++) {
        int4 c4 = *(const int4*)(cp + kk * ND + t * 4);
        if (c4.x) nz |= 1;
        if (c4.y) nz |= 2;
        if (c4.z) nz |= 4;
        if (c4.w) nz |= 8;
    }
    int cnt = __popc(nz);
    int incl = cnt;
#pragma unroll
    for (int off = 1; off < 64; off <<= 1) {
        int o = __shfl_up(incl, off);
        if (lane >= off) incl += o;
    }
    int excl = incl - cnt;
    __shared__ int wtot[4];
    if (lane == 63) wtot[wave] = incl;
    __syncthreads();
    int base = 0;
    for (int w = 0; w < wave; w++) base += wtot[w];
    int pos = base + excl;

    const float invn = 1.0f / (float)NS;
    int* up = ucell + b * ND;
    float* wp = uw + (size_t)b * ND * NK;
#pragma unroll
    for (int q = 0; q < 4; q++) {
        if (nz & (1u << q)) {
            int cell = t * 4 + q;
            int i = cell >> 5, j = cell & 31;
            int ent = (i << 15) | (j << 5) |
                      ((i == 0) ? 1 : 0) | ((i == 31) ? 2 : 0) |
                      ((j == 0) ? 4 : 0) | ((j == 31) ? 8 : 0);
            up[pos] = ent;
            for (int kk = 0; kk < NK; kk++)
                wp[(size_t)pos * NK + kk] = (float)cp[kk * ND + cell] * invn;
            pos++;
        }
    }
    if (t == 0) nunion[b] = wtot[0] + wtot[1] + wtot[2] + wtot[3];
}

// ---------------- Phase 3: union gather, deep-MLP, 8 kk per block ----------------
// Grid: blk = i32*24 + bc, bc = b*3+c; blk%8 == bc%8 so all 32 blocks of one
// (b,c) image land on the same XCD (image stays L2/L3-local).
// i32 = gg(16) | kq<<4. Thread: x = t&63, y = gg*4 + (t>>6).
// Entries+weights staged once in LDS (broadcast reads). Main loop processes
// entries in chunks of 16: all 16 x-loads issued before any FMA consumes them
// (16 outstanding loads/wave x 12 waves/CU covers L3-hit latency).
// Every output element is written exactly once -> no atomics, no zero-init.
constexpr int EC = 16;
__global__ void gather_kernel(const int* __restrict__ ucell,
                              const float* __restrict__ uw,
                              const int* __restrict__ nunion,
                              const float* __restrict__ x_high,
                              float* __restrict__ out) {
    int blk = blockIdx.x;
    int bc = blk % 24;
    int ii = blk / 24;           // 0..31
    int gg = ii & 15;
    int kq = ii >> 4;            // kk half: 0 or 1
    int b = bc / 3, c = bc % 3;
    int t = threadIdx.x;
    int x = t & 63;
    int y = gg * 4 + (t >> 6);

    int m = nunion[b];

    __shared__ int lc[ND];          // 4 KB
    __shared__ float lw[ND][8];     // 32 KB

    for (int i = t; i < m; i += 256) {
        lc[i] = ucell[b * ND + i];
        const float4* wsrc =
            (const float4*)(uw + (size_t)(b * ND + i) * NK + kq * 8);
        float4 w0 = wsrc[0], w1 = wsrc[1];
        *(float4*)&lw[i][0] = w0;
        *(float4*)&lw[i][4] = w1;
    }
    __syncthreads();

    const float* xp = x_high + (size_t)bc * (NH * NW);
    int ym = y - PTOP;           // [-16, 48)
    int xm = x - PLEFT;          // [-16, 48)
    int off = ym * NW + xm;
    int mask = ((ym < 0) ? 1 : 0) | ((ym >= 32) ? 2 : 0) |
               ((xm < 0) ? 4 : 0) | ((xm >= 32) ? 8 : 0);

    float acc[8];
#pragma unroll
    for (int q = 0; q < 8; q++) acc[q] = 0.f;

    for (int base = 0; base < m; base += EC) {
        float vv[EC];
        // phase A: issue EC independent loads
#pragma unroll
        for (int j = 0; j < EC; j++) {
            int ee = base + j;
            int ent = lc[ee < m ? ee : 0];
            bool ok = (ee < m) && ((ent & mask) == 0);
            int idx = ok ? ((ent & ~15) + off) : 0;
            float v = xp[idx];
            vv[j] = ok ? v : 0.f;
        }
        // phase B: consume
#pragma unroll
        for (int j = 0; j < EC; j++) {
            int ee = base + j;
            int es = ee < m ? ee : 0;
            float4 wa = *(const float4*)&lw[es][0];
            float4 wb = *(const float4*)&lw[es][4];
            float v = vv[j];
            acc[0] += wa.x * v; acc[1] += wa.y * v;
            acc[2] += wa.z * v; acc[3] += wa.w * v;
            acc[4] += wb.x * v; acc[5] += wb.y * v;
            acc[6] += wb.z * v; acc[7] += wb.w * v;
        }
    }

#pragma unroll
    for (int q = 0; q < 8; q++) {
        int kk = kq * 8 + q;
        int o = ((b * NK + kk) * NC + c) * (NP * NP) + y * NP + x;
        out[o] = acc[q];
    }
}

extern "C" void kernel_launch(void* const* d_in, const int* in_sizes, int n_in,
                              void* d_out, int out_size, void* d_ws, size_t ws_size,
                              hipStream_t stream) {
    const float* scores = (const float*)d_in[0];
    const float* x_high = (const float*)d_in[1];
    const float* noise  = (const float*)d_in[2];

    char* ws = (char*)d_ws;
    float* s_norm = (float*)ws;                            // 32 KB
    int* counts   = (int*)(ws + 32 * 1024);                // 512 KB (int4-aligned)
    int* ucell    = (int*)(ws + 544 * 1024);               // 32 KB
    float* uw     = (float*)(ws + 576 * 1024);             // 512 KB
    int* nunion   = (int*)(ws + 1088 * 1024);              // 32 B

    normalize_kernel<<<64, 256, 0, stream>>>(scores, s_norm, counts);
    topk_kernel<<<NB * NS / 4, 256, 0, stream>>>(s_norm, noise, counts);
    union_kernel<<<NB, 256, 0, stream>>>(counts, ucell, uw, nunion);
    gather_kernel<<<24 * 32, 256, 0, stream>>>(ucell, uw, nunion, x_high,
                                               (float*)d_out);
}